// Round 3
// baseline (3428.080 us; speedup 1.0000x reference)
//
#include <hip/hip_runtime.h>
#include <math.h>

#define T_SEQ  8192
#define EMBED  27
#define HIDDEN 30
#define GATES  (4 * HIDDEN)   // 120
#define GX_TOK 16

typedef float v2f __attribute__((ext_vector_type(2)));
typedef int   v2i __attribute__((ext_vector_type(2)));

#if defined(__has_builtin)
#if __has_builtin(__builtin_amdgcn_permlane32_swap)
#define HAS_PLS 1
#endif
#endif
#ifndef HAS_PLS
#define HAS_PLS 0
#endif

// sigmoid via hw exp2 + hw rcp + one Newton step (~0.5 ulp).
// Clamp exp2 arg so huge negatives can't produce inf -> NaN downstream.
__device__ __forceinline__ float sig_nr(float x) {
    float a = fminf(-1.44269504088896340736f * x, 80.0f);
    float e = exp2f(a);
    float d = 1.0f + e;
    float r = __builtin_amdgcn_rcpf(d);
    return r * (2.0f - d * r);
}

// Cross-half exchange: every lane gets the value held by lane^32.
// Direction-proof: permlane32_swap returns both updated registers; `pick0`
// (computed once from a runtime lane-id probe) selects the element that
// holds the opposite half's value for this lane, under either HW direction.
__device__ __forceinline__ float xhalf(float v, bool pick0) {
#if HAS_PLS
    v2i r = __builtin_amdgcn_permlane32_swap(
        __float_as_int(v), __float_as_int(v), false, false);
    return __int_as_float(pick0 ? r[0] : r[1]);
#else
    (void)pick0;
    return __shfl_xor(v, 32, 64);
#endif
}

__device__ __forceinline__ bool probe_pick0(int lane, int half) {
#if HAS_PLS
    v2i pr = __builtin_amdgcn_permlane32_swap(lane, lane, false, false);
    int f0 = __builtin_amdgcn_readfirstlane(pr[0]);   // 32 if r0.lo = src.hi
    bool dirA = (f0 == 32);
    return (half == 0) ? dirA : !dirA;
#else
    (void)lane; (void)half;
    return true;
#endif
}

// ---------------- Phase 1: gx[t][j] = emb[tok[t]] . W_ih[j] + b_ih[j] + b_hh[j]
// 512 blocks x 128 threads; 16 tokens/block, W_ih rows in registers,
// double-buffered embedding gather in LDS (sync separates every read from
// the next write of the same buffer).
__global__ __launch_bounds__(128) void gx_kernel(
        const int* __restrict__ tokens, const float* __restrict__ emb,
        const float* __restrict__ W_ih, const float* __restrict__ b_ih,
        const float* __restrict__ b_hh, float* __restrict__ gx) {
    const int tid = threadIdx.x;
    const int t0  = blockIdx.x * GX_TOK;

    float w[EMBED];
    float bias = 0.0f;
    if (tid < GATES) {
        #pragma unroll
        for (int e = 0; e < EMBED; ++e) w[e] = W_ih[tid * EMBED + e];
        bias = b_ih[tid] + b_hh[tid];
    }

    __shared__ float xbuf[2][EMBED];
    {
        int tok = tokens[t0];
        if (tid < EMBED) xbuf[0][tid] = emb[(size_t)tok * EMBED + tid];
    }
    __syncthreads();

    for (int i = 0; i < GX_TOK; ++i) {
        if (i + 1 < GX_TOK && tid < EMBED) {
            int tok = tokens[t0 + i + 1];
            xbuf[(i + 1) & 1][tid] = emb[(size_t)tok * EMBED + tid];
        }
        if (tid < GATES) {
            float acc = bias;
            #pragma unroll
            for (int e = 0; e < EMBED; ++e)
                acc = fmaf(xbuf[i & 1][e], w[e], acc);
            gx[(t0 + i) * GATES + tid] = acc;
        }
        __syncthreads();
    }
}

// ---------------- Phase 2: serial LSTM scan, single wave, 1 wave/EU.
// Lane map: half0 lane k -> rows i[k], g[k];  half1 lane k -> rows f[k], o[k].
// h broadcast via readlane->SGPR fused into the next step's FMA chain.
// Weights/acc as float2 so adjacent FMAs can SLP-fuse to v_pk_fma_f32.
__global__ __launch_bounds__(64, 1) void scan_kernel(
        const float* __restrict__ gx, const float* __restrict__ W_hh,
        const float* __restrict__ W_lin, const float* __restrict__ b_lin,
        float* __restrict__ out) {
    const int lane = threadIdx.x;
    const int half = lane >> 5;
    const int k    = lane & 31;
    const int kk   = (k < HIDDEN) ? k : 0;
    const int row_a = (half == 0) ? kk              : HIDDEN + kk;       // i | f
    const int row_b = (half == 0) ? 2 * HIDDEN + kk : 3 * HIDDEN + kk;   // g | o

    const bool pick0 = probe_pick0(lane, half);

    // half0's b-gate is tanh: tanh(x) = 2*sigmoid(2x) - 1
    const float bscale = (half == 0) ? 2.0f : 1.0f;
    const float oscale = (half == 0) ? 2.0f : 1.0f;
    const float obias  = (half == 0) ? -1.0f : 0.0f;

    v2f w2[HIDDEN];
    #pragma unroll
    for (int j = 0; j < HIDDEN; ++j) {
        w2[j][0] = W_hh[row_a * HIDDEN + j];
        w2[j][1] = W_hh[row_b * HIDDEN + j];
    }

    float c = 0.0f, hn = 0.0f;
    v2f acc;
    acc[0] = gx[row_a];                 // h0 = 0 -> gates(0) = gx[0]
    acc[1] = gx[row_b];
    v2f g0, g1;                         // prefetch t=1, t=2
    g0[0] = gx[1 * GATES + row_a]; g0[1] = gx[1 * GATES + row_b];
    g1[0] = gx[2 * GATES + row_a]; g1[1] = gx[2 * GATES + row_b];

#define LSTM_STEP(G, TPRE)                                                   \
    {                                                                        \
        float va = sig_nr(acc[0]);                 /* i | f           */     \
        float sb = sig_nr(acc[1] * bscale);                                  \
        float vb = fmaf(oscale, sb, obias);        /* tanh g | o      */     \
        float sf = xhalf(va, pick0);               /* half0: sig f    */     \
        float so = xhalf(vb, pick0);               /* half0: sig o    */     \
        c = fmaf(sf, c, va * vb);                  /* f*c + i*g       */     \
        float tc = fmaf(2.0f, sig_nr(2.0f * c), -1.0f);  /* tanh c    */     \
        hn = so * tc;                              /* h (half0 k<30)  */     \
        int tp = (TPRE) < T_SEQ ? (TPRE) : T_SEQ - 1;                        \
        v2f ng = G;                                                          \
        G[0] = gx[tp * GATES + row_a];                                       \
        G[1] = gx[tp * GATES + row_b];                                       \
        acc = ng;                                                            \
        _Pragma("unroll")                                                    \
        for (int j = 0; j < HIDDEN; ++j) {                                   \
            float hj = __uint_as_float((unsigned)__builtin_amdgcn_readlane(  \
                (int)__float_as_uint(hn), j));                               \
            acc[0] = fmaf(hj, w2[j][0], acc[0]);                             \
            acc[1] = fmaf(hj, w2[j][1], acc[1]);                             \
        }                                                                    \
    }

    for (int t = 0; t < T_SEQ; t += 2) {
        LSTM_STEP(g0, t + 3)
        LSTM_STEP(g1, t + 4)
    }
#undef LSTM_STEP

    // head: out = h_last . W_lin + b_lin
    float s = b_lin[0];
    #pragma unroll
    for (int j = 0; j < HIDDEN; ++j) {
        float hj = __uint_as_float((unsigned)__builtin_amdgcn_readlane(
            (int)__float_as_uint(hn), j));
        s = fmaf(hj, W_lin[j], s);
    }
    if (lane == 0) out[0] = s;
}

// ---------------- Fallback: fused scan computing gx on the fly (ws too small)
__global__ __launch_bounds__(64, 1) void scan_fused(
        const int* __restrict__ tokens, const float* __restrict__ emb,
        const float* __restrict__ W_ih, const float* __restrict__ b_ih,
        const float* __restrict__ b_hh, const float* __restrict__ W_hh,
        const float* __restrict__ W_lin, const float* __restrict__ b_lin,
        float* __restrict__ out) {
    const int lane = threadIdx.x;
    const int half = lane >> 5;
    const int k    = lane & 31;
    const int kk   = (k < HIDDEN) ? k : 0;
    const int row_a = (half == 0) ? kk              : HIDDEN + kk;
    const int row_b = (half == 0) ? 2 * HIDDEN + kk : 3 * HIDDEN + kk;
    const bool pick0 = probe_pick0(lane, half);
    const float bscale = (half == 0) ? 2.0f : 1.0f;
    const float oscale = (half == 0) ? 2.0f : 1.0f;
    const float obias  = (half == 0) ? -1.0f : 0.0f;

    float wa[HIDDEN], wb[HIDDEN];
    #pragma unroll
    for (int j = 0; j < HIDDEN; ++j) {
        wa[j] = W_hh[row_a * HIDDEN + j];
        wb[j] = W_hh[row_b * HIDDEN + j];
    }
    float wia[EMBED], wib[EMBED];
    #pragma unroll
    for (int e = 0; e < EMBED; ++e) {
        wia[e] = W_ih[row_a * EMBED + e];
        wib[e] = W_ih[row_b * EMBED + e];
    }
    const float bias_a = b_ih[row_a] + b_hh[row_a];
    const float bias_b = b_ih[row_b] + b_hh[row_b];

    float c = 0.0f, hn = 0.0f;

    for (int t = 0; t < T_SEQ; ++t) {
        const int tok = tokens[t];
        float acc_a = bias_a, acc_b = bias_b;
        #pragma unroll
        for (int e = 0; e < EMBED; ++e) {
            float x = emb[(size_t)tok * EMBED + e];
            acc_a = fmaf(x, wia[e], acc_a);
            acc_b = fmaf(x, wib[e], acc_b);
        }
        #pragma unroll
        for (int j = 0; j < HIDDEN; ++j) {
            float hj = __uint_as_float((unsigned)__builtin_amdgcn_readlane(
                (int)__float_as_uint(hn), j));
            acc_a = fmaf(hj, wa[j], acc_a);
            acc_b = fmaf(hj, wb[j], acc_b);
        }
        float va = sig_nr(acc_a);
        float sb = sig_nr(acc_b * bscale);
        float vb = fmaf(oscale, sb, obias);
        float sf = xhalf(va, pick0);
        float so = xhalf(vb, pick0);
        c = fmaf(sf, c, va * vb);
        float tc = fmaf(2.0f, sig_nr(2.0f * c), -1.0f);
        hn = so * tc;
    }

    float s = b_lin[0];
    #pragma unroll
    for (int j = 0; j < HIDDEN; ++j) {
        float hj = __uint_as_float((unsigned)__builtin_amdgcn_readlane(
            (int)__float_as_uint(hn), j));
        s = fmaf(hj, W_lin[j], s);
    }
    if (lane == 0) out[0] = s;
}

extern "C" void kernel_launch(void* const* d_in, const int* in_sizes, int n_in,
                              void* d_out, int out_size, void* d_ws, size_t ws_size,
                              hipStream_t stream) {
    const int*   tokens = (const int*)d_in[0];
    const float* emb    = (const float*)d_in[1];
    const float* W_ih   = (const float*)d_in[2];
    const float* W_hh   = (const float*)d_in[3];
    const float* b_ih   = (const float*)d_in[4];
    const float* b_hh   = (const float*)d_in[5];
    const float* W_lin  = (const float*)d_in[6];
    const float* b_lin  = (const float*)d_in[7];
    float* out = (float*)d_out;

    const size_t need = (size_t)T_SEQ * GATES * sizeof(float);  // 3.93 MB
    if (ws_size >= need) {
        float* gx = (float*)d_ws;
        gx_kernel<<<T_SEQ / GX_TOK, 128, 0, stream>>>(tokens, emb, W_ih, b_ih, b_hh, gx);
        scan_kernel<<<1, 64, 0, stream>>>(gx, W_hh, W_lin, b_lin, out);
    } else {
        scan_fused<<<1, 64, 0, stream>>>(tokens, emb, W_ih, b_ih, b_hh,
                                         W_hh, W_lin, b_lin, out);
    }
}

// Round 4
// 2237.838 us; speedup vs baseline: 1.5319x; 1.5319x over previous
//
#include <hip/hip_runtime.h>
#include <math.h>

#define T_SEQ  8192
#define EMBED  27
#define HIDDEN 30
#define GATES  120
#define SLOTS  60          // float2 slots per timestep in the interleaved gx2

typedef float v2f __attribute__((ext_vector_type(2)));
typedef int   v2i __attribute__((ext_vector_type(2)));

#if defined(__has_builtin)
#if __has_builtin(__builtin_amdgcn_permlane32_swap)
#define HAS_PLS 1
#endif
#endif
#ifndef HAS_PLS
#define HAS_PLS 0
#endif

// sigmoid via hw exp2 + hw rcp (~1 ulp, no Newton). Clamp exp2 arg so huge
// negatives can't produce inf downstream.
__device__ __forceinline__ float sig1(float x) {
    float a = fminf(-1.44269504088896340736f * x, 80.0f);
    return __builtin_amdgcn_rcpf(1.0f + exp2f(a));
}

// Cross-half exchange: every lane gets the value held by lane^32.
// Direction-proof (identical to round-3 machinery that verified absmax 0.0):
// permlane32_swap returns both updated registers; `pick0` (from a runtime
// lane-id probe) selects the element holding the opposite half's value.
__device__ __forceinline__ float xhalf(float v, bool pick0) {
#if HAS_PLS
    v2i r = __builtin_amdgcn_permlane32_swap(
        __float_as_int(v), __float_as_int(v), false, false);
    return __int_as_float(pick0 ? r[0] : r[1]);
#else
    (void)pick0;
    return __shfl_xor(v, 32, 64);
#endif
}

__device__ __forceinline__ bool probe_pick0(int lane, int half) {
#if HAS_PLS
    v2i pr = __builtin_amdgcn_permlane32_swap(lane, lane, false, false);
    int f0 = __builtin_amdgcn_readfirstlane(pr[0]);   // 32 if r0.lo = src.hi
    bool dirA = (f0 == 32);
    return (half == 0) ? dirA : !dirA;
#else
    (void)lane; (void)half;
    return true;
#endif
}

// ---------------- Phase 1: interleaved gate pre-activations.
// gx2[t] is 60 float2 slots matching scan lanes:
//   slot k    (k<30): (i_k, 2*g_k)   -> scan lanes 0..29
//   slot 30+k (k<30): (f_k, o_k)     -> scan lanes 32..61
// (g rows pre-scaled by 2 for tanh(x) = 2*sigmoid(2x)-1.)
__global__ __launch_bounds__(128) void gx_kernel(
        const int* __restrict__ tokens, const float* __restrict__ emb,
        const float* __restrict__ W_ih, const float* __restrict__ b_ih,
        const float* __restrict__ b_hh, float* __restrict__ gx2) {
    const int t   = blockIdx.x;
    const int tid = threadIdx.x;
    __shared__ float xs[EMBED];
    if (tid < EMBED) xs[tid] = emb[(size_t)tokens[t] * EMBED + tid];
    __syncthreads();
    if (tid < GATES) {
        const int row = tid;
        float acc = b_ih[row] + b_hh[row];
        #pragma unroll
        for (int e = 0; e < EMBED; ++e)
            acc = fmaf(xs[e], W_ih[row * EMBED + e], acc);
        const int   slot  = (row < 60) ? row : row - 60;   // 0..59
        const int   comp  = (row < 60) ? 0 : 1;
        const float scale = (row >= 60 && row < 90) ? 2.0f : 1.0f;  // g rows
        gx2[(size_t)t * (2 * SLOTS) + slot * 2 + comp] = scale * acc;
    }
}

// ---------------- Phase 2: serial LSTM scan, single wave, 1 wave/EU.
// half0 lane k: rows i[k] (acc.x), g[k] (acc.y, pre-scaled 2x).
// half1 lane k: rows f[k] (acc.x), o[k] (acc.y).
// One coalesced dwordx2 gx load per lane per step, 8-deep prefetch.
// h broadcast via readlane fused into 4-way-split FMA chains.
__global__ __launch_bounds__(64, 1) void scan_kernel(
        const float* __restrict__ gx2, const float* __restrict__ W_hh,
        const float* __restrict__ W_lin, const float* __restrict__ b_lin,
        float* __restrict__ out) {
    const int lane = threadIdx.x;
    const int half = lane >> 5;
    const int k    = lane & 31;
    const int kk   = (k < HIDDEN) ? k : HIDDEN - 1;   // clamp idle lanes
    const int row_a = (half == 0) ? kk      : 30 + kk;   // i | f
    const int row_b = (half == 0) ? 60 + kk : 90 + kk;   // g | o

    const bool pick0 = probe_pick0(lane, half);

    // half0: vb = 2*tanh(g) = 4*sig(2g) - 2 (acc.y already holds 2g-preact)
    // half1: vb = sig(o)
    const float wbs    = (half == 0) ? 2.0f  : 1.0f;   // g-row weights x2
    const float oscale = (half == 0) ? 4.0f  : 1.0f;
    const float obias  = (half == 0) ? -2.0f : 0.0f;

    float wa[HIDDEN], wb[HIDDEN];
    #pragma unroll
    for (int j = 0; j < HIDDEN; ++j) {
        wa[j] = W_hh[row_a * HIDDEN + j];
        wb[j] = wbs * W_hh[row_b * HIDDEN + j];
    }

    const int slot = (half == 0) ? kk : 30 + kk;
    const v2f* gp = (const v2f*)gx2 + slot;            // advance by SLOTS per t

    v2f acc = gp[0];                                   // gates(0): h(-1) = 0
    v2f p0 = gp[(size_t)1 * SLOTS], p1 = gp[(size_t)2 * SLOTS];
    v2f p2 = gp[(size_t)3 * SLOTS], p3 = gp[(size_t)4 * SLOTS];
    v2f p4 = gp[(size_t)5 * SLOTS], p5 = gp[(size_t)6 * SLOTS];
    v2f p6 = gp[(size_t)7 * SLOTS], p7 = gp[(size_t)8 * SLOTS];

    float cd = 0.0f;   // tracks 2*c
    float hn = 0.0f;

#define RL(J) __uint_as_float((unsigned)__builtin_amdgcn_readlane( \
        (int)__float_as_uint(hn), (J)))

#define STEP(P, TN)                                                          \
    {                                                                        \
        float va = sig1(acc[0]);                  /* sig i | sig f    */     \
        float sb = sig1(acc[1]);                  /* sig 2g | sig o   */     \
        float vb = fmaf(oscale, sb, obias);       /* 2tanh g | sig o  */     \
        float sf = xhalf(va, pick0);              /* half0: sig f     */     \
        float so = xhalf(vb, pick0);              /* half0: sig o     */     \
        cd = fmaf(sf, cd, va * vb);               /* 2c = f*2c + i*2g */     \
        float tc = fmaf(2.0f, sig1(cd), -1.0f);   /* tanh c           */     \
        hn = so * tc;                                                        \
        v2f ng = P;                                                          \
        int tn = (TN) < T_SEQ ? (TN) : (T_SEQ - 1);                          \
        P = gp[(size_t)tn * SLOTS];                                          \
        float h0 = RL(0), h1 = RL(1), h2 = RL(2), h3 = RL(3);                \
        float a0 = fmaf(h0, wa[0], ng[0]);                                   \
        float b0 = fmaf(h0, wb[0], ng[1]);                                   \
        float a1 = h1 * wa[1], b1 = h1 * wb[1];                              \
        float a2 = h2 * wa[2], b2 = h2 * wb[2];                              \
        float a3 = h3 * wa[3], b3 = h3 * wb[3];                              \
        _Pragma("unroll")                                                    \
        for (int j = 4; j + 4 <= HIDDEN; j += 4) {                           \
            float hA = RL(j), hB = RL(j + 1), hC = RL(j + 2), hD = RL(j + 3);\
            a0 = fmaf(hA, wa[j],     a0);  b0 = fmaf(hA, wb[j],     b0);     \
            a1 = fmaf(hB, wa[j + 1], a1);  b1 = fmaf(hB, wb[j + 1], b1);     \
            a2 = fmaf(hC, wa[j + 2], a2);  b2 = fmaf(hC, wb[j + 2], b2);     \
            a3 = fmaf(hD, wa[j + 3], a3);  b3 = fmaf(hD, wb[j + 3], b3);     \
        }                                                                    \
        { /* tail j = 28, 29 */                                              \
            float hE = RL(28), hF = RL(29);                                  \
            a0 = fmaf(hE, wa[28], a0);  b0 = fmaf(hE, wb[28], b0);           \
            a1 = fmaf(hF, wa[29], a1);  b1 = fmaf(hF, wb[29], b1);           \
        }                                                                    \
        acc[0] = (a0 + a1) + (a2 + a3);                                      \
        acc[1] = (b0 + b1) + (b2 + b3);                                      \
    }

    for (int t = 0; t < T_SEQ; t += 8) {
        STEP(p0, t + 9)  STEP(p1, t + 10) STEP(p2, t + 11) STEP(p3, t + 12)
        STEP(p4, t + 13) STEP(p5, t + 14) STEP(p6, t + 15) STEP(p7, t + 16)
    }
#undef STEP

    // head: out = h_last . W_lin + b_lin
    float s = b_lin[0];
    #pragma unroll
    for (int j = 0; j < HIDDEN; ++j) s = fmaf(RL(j), W_lin[j], s);
    if (lane == 0) out[0] = s;
#undef RL
}

// ---------------- Fallback: fused scan computing gx on the fly (ws too small)
__global__ __launch_bounds__(64, 1) void scan_fused(
        const int* __restrict__ tokens, const float* __restrict__ emb,
        const float* __restrict__ W_ih, const float* __restrict__ b_ih,
        const float* __restrict__ b_hh, const float* __restrict__ W_hh,
        const float* __restrict__ W_lin, const float* __restrict__ b_lin,
        float* __restrict__ out) {
    const int lane = threadIdx.x;
    const int half = lane >> 5;
    const int k    = lane & 31;
    const int kk   = (k < HIDDEN) ? k : 0;
    const int row_a = (half == 0) ? kk              : HIDDEN + kk;
    const int row_b = (half == 0) ? 2 * HIDDEN + kk : 3 * HIDDEN + kk;
    const bool pick0 = probe_pick0(lane, half);
    const float bscale = (half == 0) ? 2.0f : 1.0f;
    const float oscale = (half == 0) ? 2.0f : 1.0f;
    const float obias  = (half == 0) ? -1.0f : 0.0f;

    float wa[HIDDEN], wb[HIDDEN];
    #pragma unroll
    for (int j = 0; j < HIDDEN; ++j) {
        wa[j] = W_hh[row_a * HIDDEN + j];
        wb[j] = W_hh[row_b * HIDDEN + j];
    }
    float wia[EMBED], wib[EMBED];
    #pragma unroll
    for (int e = 0; e < EMBED; ++e) {
        wia[e] = W_ih[row_a * EMBED + e];
        wib[e] = W_ih[row_b * EMBED + e];
    }
    const float bias_a = b_ih[row_a] + b_hh[row_a];
    const float bias_b = b_ih[row_b] + b_hh[row_b];

    float c = 0.0f, hn = 0.0f;

    for (int t = 0; t < T_SEQ; ++t) {
        const int tok = tokens[t];
        float acc_a = bias_a, acc_b = bias_b;
        #pragma unroll
        for (int e = 0; e < EMBED; ++e) {
            float x = emb[(size_t)tok * EMBED + e];
            acc_a = fmaf(x, wia[e], acc_a);
            acc_b = fmaf(x, wib[e], acc_b);
        }
        #pragma unroll
        for (int j = 0; j < HIDDEN; ++j) {
            float hj = __uint_as_float((unsigned)__builtin_amdgcn_readlane(
                (int)__float_as_uint(hn), j));
            acc_a = fmaf(hj, wa[j], acc_a);
            acc_b = fmaf(hj, wb[j], acc_b);
        }
        float va = sig1(acc_a);
        float sb = sig1(acc_b * bscale);
        float vb = fmaf(oscale, sb, obias);
        float sf = xhalf(va, pick0);
        float so = xhalf(vb, pick0);
        c = fmaf(sf, c, va * vb);
        float tc = fmaf(2.0f, sig1(2.0f * c), -1.0f);
        hn = so * tc;
    }

    float s = b_lin[0];
    #pragma unroll
    for (int j = 0; j < HIDDEN; ++j) {
        float hj = __uint_as_float((unsigned)__builtin_amdgcn_readlane(
            (int)__float_as_uint(hn), j));
        s = fmaf(hj, W_lin[j], s);
    }
    if (lane == 0) out[0] = s;
}

extern "C" void kernel_launch(void* const* d_in, const int* in_sizes, int n_in,
                              void* d_out, int out_size, void* d_ws, size_t ws_size,
                              hipStream_t stream) {
    const int*   tokens = (const int*)d_in[0];
    const float* emb    = (const float*)d_in[1];
    const float* W_ih   = (const float*)d_in[2];
    const float* W_hh   = (const float*)d_in[3];
    const float* b_ih   = (const float*)d_in[4];
    const float* b_hh   = (const float*)d_in[5];
    const float* W_lin  = (const float*)d_in[6];
    const float* b_lin  = (const float*)d_in[7];
    float* out = (float*)d_out;

    const size_t need = (size_t)T_SEQ * GATES * sizeof(float);  // 3.93 MB
    if (ws_size >= need) {
        float* gx2 = (float*)d_ws;
        gx_kernel<<<T_SEQ, 128, 0, stream>>>(tokens, emb, W_ih, b_ih, b_hh, gx2);
        scan_kernel<<<1, 64, 0, stream>>>(gx2, W_hh, W_lin, b_lin, out);
    } else {
        scan_fused<<<1, 64, 0, stream>>>(tokens, emb, W_ih, b_ih, b_hh,
                                         W_hh, W_lin, b_lin, out);
    }
}